// Round 7
// baseline (268.565 us; speedup 1.0000x reference)
//
#include <hip/hip_runtime.h>
#include <math.h>

#define BB 256      // batch
#define CC 1024     // channels
#define CC4 (CC/4)  // row length in float4
#define MARGIN 0.5f
#define NTILE 64    // j-tiles (of 4) per row
#define JPT 4       // j's per tile
#define GRID 1024   // persistent blocks (must ALL be co-resident: VGPR<=128, LDS 32KB)
#define NTASK 2080  // triangular (ig<=jt) pair tasks

// ---------------------------------------------------------------------------
// Device-scope grid barrier: release-fence + arrive, thread-0 spins with
// s_sleep, acquire-fence, block-local barrier. All GRID blocks are
// co-resident by construction (1024 = 256 CU x 4 blocks/CU at VGPR<=128;
// LDS 32KB allows 5/CU). Counters are pre-zeroed by hipMemsetAsync.
// ---------------------------------------------------------------------------
__device__ __forceinline__ void grid_barrier(unsigned int* ctr,
                                             unsigned int target, int tid)
{
    __syncthreads();
    if (tid == 0) {
        __threadfence();                       // release our writes
        atomicAdd(ctr, 1u);
        while (atomicAdd(ctr, 0u) < target)    // device-coherent read
            __builtin_amdgcn_s_sleep(8);
        __threadfence();                       // acquire others' writes
    }
    __syncthreads();
}

// ---------------------------------------------------------------------------
// Fused persistent kernel: phase 1 mcsq -> barrier -> phase 2 pair tasks
// (grid-strided) -> barrier -> phase 3 final reduce. Per-(i,j) arithmetic,
// reduction trees, and output slots are IDENTICAL to R4/R6 -> bit-exact.
// ---------------------------------------------------------------------------
__global__ __launch_bounds__(256) void fused_kernel(
    const float* __restrict__ x, const int* __restrict__ targets,
    const int* __restrict__ subs, const int* __restrict__ m_count_p,
    float* __restrict__ mcsq,
    float* __restrict__ pmax, float* __restrict__ pmin,
    float* __restrict__ pmaxT, float* __restrict__ pminT,
    float* __restrict__ acc, unsigned int* __restrict__ cnt_g,
    unsigned int* __restrict__ bar, float* __restrict__ out)
{
    const int tid  = threadIdx.x;
    const int lane = tid & 63;
    const int w    = tid >> 6;
    const int bid  = blockIdx.x;
    const int g    = bid * 4 + w;             // global wave id (phases 1 & 3)

    __shared__ float lds[8192];               // 32 KB: x rows + mcsq rows
    float4* lds4 = (float4*)lds;

    const float4* x4 = (const float4*)x;

    // ================= PHASE 1: mcsq[i,c] = m_counts[i,c]^2 ================
    if (g < BB) {
        const int i = g;
        const int ti = targets[i], si = subs[i];
        int mc = *m_count_p;
        if (mc > 8) mc = 8;

        unsigned long long masks[4];
        #pragma unroll
        for (int q = 0; q < 4; ++q) {
            const int j = q * 64 + lane;
            masks[q] = __ballot(targets[j] == ti && subs[j] == si);
        }
        int idx[8];
        int cnt = 0;
        for (int q = 0; q < 4 && cnt < mc; ++q) {
            unsigned long long m = masks[q];
            while (m && cnt < mc) {
                const int b = __ffsll(m) - 1;
                idx[cnt++] = q * 64 + b;
                m &= m - 1;
            }
        }
        for (int q = 0; q < 4 && cnt < mc; ++q) {   // stable-argsort padding
            unsigned long long m = ~masks[q];
            while (m && cnt < mc) {
                const int b = __ffsll(m) - 1;
                idx[cnt++] = q * 64 + b;
                m &= m - 1;
            }
        }

        float4 xi[4];
        #pragma unroll
        for (int t = 0; t < 4; ++t) xi[t] = x4[(long)i * CC4 + lane + 64 * t];

        float4 c4[4];
        #pragma unroll
        for (int t = 0; t < 4; ++t) c4[t] = make_float4(0.f, 0.f, 0.f, 0.f);

        for (int k = 0; k < cnt; ++k) {
            float4 ad[4];
            float s = 0.f;
            #pragma unroll
            for (int t = 0; t < 4; ++t) {
                const float4 xj = x4[(long)idx[k] * CC4 + lane + 64 * t];
                ad[t].x = fabsf(xi[t].x - xj.x);
                ad[t].y = fabsf(xi[t].y - xj.y);
                ad[t].z = fabsf(xi[t].z - xj.z);
                ad[t].w = fabsf(xi[t].w - xj.w);
                s += ad[t].x + ad[t].y + ad[t].z + ad[t].w;
            }
            #pragma unroll
            for (int off = 32; off > 0; off >>= 1) s += __shfl_xor(s, off, 64);
            const float thr = s * (MARGIN / CC);   // 0.5 * mean
            #pragma unroll
            for (int t = 0; t < 4; ++t) {
                c4[t].x += (ad[t].x < thr) ? 1.f : 0.f;
                c4[t].y += (ad[t].y < thr) ? 1.f : 0.f;
                c4[t].z += (ad[t].z < thr) ? 1.f : 0.f;
                c4[t].w += (ad[t].w < thr) ? 1.f : 0.f;
            }
        }
        float4* m4o = (float4*)mcsq;
        #pragma unroll
        for (int t = 0; t < 4; ++t) {
            float4 o;
            o.x = c4[t].x * c4[t].x;
            o.y = c4[t].y * c4[t].y;
            o.z = c4[t].z * c4[t].z;
            o.w = c4[t].w * c4[t].w;
            m4o[(long)i * CC4 + lane + 64 * t] = o;
        }
    }

    grid_barrier(&bar[0], GRID, tid);

    // ================= PHASE 2: triangular pair tasks ======================
    const float4* m4 = (const float4*)mcsq;

    for (int T = bid; T < NTASK; T += GRID) {
        // decode T -> (jt, ig): T = jt(jt+1)/2 + ig, ig in [0, jt]
        int jt = (int)((sqrtf(8.0f * (float)T + 1.0f) - 1.0f) * 0.5f);
        if (jt < 0) jt = 0;
        if (jt > 63) jt = 63;
        while (jt > 0 && (jt * (jt + 1)) / 2 > T) --jt;
        while (((jt + 1) * (jt + 2)) / 2 <= T) ++jt;
        const int ig = T - (jt * (jt + 1)) / 2;   // 0..jt
        const int i  = ig * 4 + w;                // wave's i-row
        const int j0 = jt * JPT;

        __syncthreads();                          // all waves done with LDS

        // stage 4 j-rows of x and mcsq into LDS (256 thr x 8 float4)
        {
            float4 st[8];
            #pragma unroll
            for (int q = 0; q < 4; ++q) {
                st[q]     = x4[(long)(j0 + q) * CC4 + tid];
                st[4 + q] = m4[(long)(j0 + q) * CC4 + tid];
            }
            #pragma unroll
            for (int q = 0; q < 8; ++q) lds4[q * 256 + tid] = st[q];
        }
        __syncthreads();

        const int ti = targets[i];
        int tj[4];
        #pragma unroll
        for (int q = 0; q < 4; ++q) tj[q] = targets[j0 + q];

        float4 xi[4], mi[4];
        #pragma unroll
        for (int t = 0; t < 4; ++t) {
            const int c4 = lane + 64 * t;
            xi[t] = x4[(long)i * CC4 + c4];
            mi[t] = m4[(long)i * CC4 + c4];
        }

        const float4* lx = lds4;                  // x rows: row*256 + c4
        const float4* lm = lds4 + 1024;           // mcsq rows

        float mx = 0.f, mn = INFINITY;

        #pragma unroll
        for (int jj = 0; jj < JPT; ++jj) {
            const int j = j0 + jj;

            float4 xa[4];
            float s = 0.f;
            #pragma unroll
            for (int t = 0; t < 4; ++t) {
                xa[t] = lx[jj * 256 + lane + 64 * t];
                s += fabsf(xi[t].x - xa[t].x) + fabsf(xi[t].y - xa[t].y)
                   + fabsf(xi[t].z - xa[t].z) + fabsf(xi[t].w - xa[t].w);
            }

            float4 ma[4];
            #pragma unroll
            for (int t = 0; t < 4; ++t) ma[t] = lm[jj * 256 + lane + 64 * t];

            #pragma unroll
            for (int off = 32; off > 0; off >>= 1) s += __shfl_xor(s, off, 64);
            const float thr = s * (MARGIN / CC);

            float ids = 0.f, md = 0.f;
            #pragma unroll
            for (int t = 0; t < 4; ++t) {
                #pragma unroll
                for (int u = 0; u < 4; ++u) {
                    const float xiv = (&xi[t].x)[u];
                    const float miv = (&mi[t].x)[u];
                    const float xav = (&xa[t].x)[u];
                    const float mav = (&ma[t].x)[u];
                    const float d = xiv - xav;
                    const float q = d * d;
                    ids += (fabsf(d) < thr) ? q : 0.f;
                    md  += q * miv * mav;
                }
            }
            #pragma unroll
            for (int off = 32; off > 0; off >>= 1) {
                ids += __shfl_xor(ids, off, 64);
                md  += __shfl_xor(md,  off, 64);
            }

            const float mod = sqrtf(fmaxf(md, 1e-12f));
            float idv = sqrtf(fmaxf(ids, 1e-12f));
            mx = fmaxf(mx, mod);
            if (tj[jj] != ti) mn = fminf(mn, idv); else idv = INFINITY;

            if (lane == 0) {                      // j-side (transposed) partial
                pmaxT[j * BB + i] = mod;
                pminT[j * BB + i] = idv;
            }
        }
        if (lane == 0) {                          // i-side partials
            pmax[i * NTILE + jt] = mx;
            pmin[i * NTILE + jt] = mn;
        }
    }

    grid_barrier(&bar[1], GRID, tid);

    // ================= PHASE 3: final reduce (waves g < 256) ===============
    if (g < BB) {
        const int i = g;
        const int s = i >> 2;
        float mx = 0.f, mn = INFINITY;
        const int t = s + lane;
        if (t < NTILE) {
            mx = fmaxf(mx, pmax[i * NTILE + t]);
            mn = fminf(mn, pmin[i * NTILE + t]);
        }
        const int pv = 4 * s + 4;       // transposed valid i' count
        #pragma unroll
        for (int q = 0; q < 4; ++q) {
            const int c = lane + 64 * q;
            if (c < pv) {
                mx = fmaxf(mx, pmaxT[i * BB + c]);
                mn = fminf(mn, pminT[i * BB + c]);
            }
        }
        #pragma unroll
        for (int off = 32; off > 0; off >>= 1) {
            mx = fmaxf(mx, __shfl_xor(mx, off, 64));
            mn = fminf(mn, __shfl_xor(mn, off, 64));
        }
        if (lane == 0) {
            const float per = fmaxf(mx * 10.f - mn, 0.f);
            atomicAdd(acc, per * (1.0f / BB));
            __threadfence();
            const unsigned int old = atomicAdd(cnt_g, 1u);
            if (old == BB - 1) {
                __threadfence();
                out[0] = atomicAdd(acc, 0.0f);   // device-coherent read-back
            }
        }
    }
}

extern "C" void kernel_launch(void* const* d_in, const int* in_sizes, int n_in,
                              void* d_out, int out_size, void* d_ws, size_t ws_size,
                              hipStream_t stream)
{
    const float* x       = (const float*)d_in[0];
    const int*   targets = (const int*)d_in[1];
    const int*   subs    = (const int*)d_in[2];
    const int*   m_count = (const int*)d_in[3];
    float* out  = (float*)d_out;

    float* mcsq  = (float*)d_ws;                  // BB*CC floats = 1 MB
    float* pmax  = mcsq  + (long)BB * CC;         // BB*NTILE
    float* pmin  = pmax  + BB * NTILE;            // BB*NTILE
    float* pmaxT = pmin  + BB * NTILE;            // BB*BB
    float* pminT = pmaxT + BB * BB;               // BB*BB
    float* acc   = pminT + BB * BB;               // 1 float
    unsigned int* cnt_g = (unsigned int*)(acc + 1);   // 1 uint
    unsigned int* bar   = cnt_g + 1;                  // 2 uints

    // zero acc, cnt_g, bar[0], bar[1] (16 bytes) — capture-safe async memset
    hipMemsetAsync(acc, 0, 16, stream);

    fused_kernel<<<GRID, 256, 0, stream>>>(
        x, targets, subs, m_count, mcsq, pmax, pmin, pmaxT, pminT,
        acc, cnt_g, bar, out);
}

// Round 10
// 87.444 us; speedup vs baseline: 3.0713x; 3.0713x over previous
//
#include <hip/hip_runtime.h>
#include <math.h>

#define BB 256      // batch
#define CC 1024     // channels
#define CC4 (CC/4)  // row length in float4
#define MARGIN 0.5f
#define NTILE 64    // j-tiles (of 4) per row
#define JPT 4       // j's per tile

// ---------------------------------------------------------------------------
// Bit-exact wave reduction (HW-VERIFIED in R5 and R6: absmax 0.0).
// Same pairings as the xor-butterfly (32,16,8,4,2,1): steps 32/16 via
// shfl_xor (LDS pipe, 2 hops), steps 8/4/2/1 on the VALU pipe via DPP
// (row_ror:8 == xor8; row_ror:4 lane-0-tree exact; quad_perms == xor2/xor1).
// The old butterfly left ALL lanes with the identical lane-0-tree value;
// readfirstlane broadcasts exactly that value.
// ---------------------------------------------------------------------------
template<int CTRL>
__device__ __forceinline__ float dpp_add(float v) {
    const int pi = __builtin_amdgcn_update_dpp(
        0, __float_as_int(v), CTRL, 0xF, 0xF, false);
    return v + __int_as_float(pi);
}
__device__ __forceinline__ float wred(float v) {
    v += __shfl_xor(v, 32, 64);
    v += __shfl_xor(v, 16, 64);
    v = dpp_add<0x128>(v);   // row_ror:8  == xor8
    v = dpp_add<0x124>(v);   // row_ror:4  (lane-0 tree exact)
    v = dpp_add<0x4E>(v);    // quad_perm 2,3,0,1 == xor2
    v = dpp_add<0xB1>(v);    // quad_perm 1,0,3,2 == xor1
    return __int_as_float(__builtin_amdgcn_readfirstlane(__float_as_int(v)));
}

// ---------------------------------------------------------------------------
// Kernel A: mcsq[i,c] = m_counts[i,c]^2 (float). Unchanged (R4 form).
// ---------------------------------------------------------------------------
__global__ __launch_bounds__(64) void mcsq_kernel(
    const float* __restrict__ x, const int* __restrict__ targets,
    const int* __restrict__ subs, const int* __restrict__ m_count_p,
    float* __restrict__ mcsq, float* __restrict__ acc,
    unsigned int* __restrict__ cnt_g)
{
    const int i = blockIdx.x;
    const int lane = threadIdx.x;
    if (i == 0 && lane == 0) { *acc = 0.f; *cnt_g = 0u; }
    const int ti = targets[i], si = subs[i];
    int mc = *m_count_p;
    if (mc > 8) mc = 8;

    unsigned long long masks[4];
    #pragma unroll
    for (int q = 0; q < 4; ++q) {
        const int j = q * 64 + lane;
        masks[q] = __ballot(targets[j] == ti && subs[j] == si);
    }
    int idx[8];
    int cnt = 0;
    for (int q = 0; q < 4 && cnt < mc; ++q) {
        unsigned long long m = masks[q];
        while (m && cnt < mc) {
            const int b = __ffsll(m) - 1;
            idx[cnt++] = q * 64 + b;
            m &= m - 1;
        }
    }
    for (int q = 0; q < 4 && cnt < mc; ++q) {   // stable-argsort padding
        unsigned long long m = ~masks[q];
        while (m && cnt < mc) {
            const int b = __ffsll(m) - 1;
            idx[cnt++] = q * 64 + b;
            m &= m - 1;
        }
    }

    const float4* x4 = (const float4*)x;
    float4 xi[4];
    #pragma unroll
    for (int t = 0; t < 4; ++t) xi[t] = x4[(long)i * CC4 + lane + 64 * t];

    float4 c4[4];
    #pragma unroll
    for (int t = 0; t < 4; ++t) c4[t] = make_float4(0.f, 0.f, 0.f, 0.f);

    for (int k = 0; k < cnt; ++k) {
        float4 ad[4];
        float s = 0.f;
        #pragma unroll
        for (int t = 0; t < 4; ++t) {
            const float4 xj = x4[(long)idx[k] * CC4 + lane + 64 * t];
            ad[t].x = fabsf(xi[t].x - xj.x);
            ad[t].y = fabsf(xi[t].y - xj.y);
            ad[t].z = fabsf(xi[t].z - xj.z);
            ad[t].w = fabsf(xi[t].w - xj.w);
            s += ad[t].x + ad[t].y + ad[t].z + ad[t].w;
        }
        #pragma unroll
        for (int off = 32; off > 0; off >>= 1) s += __shfl_xor(s, off, 64);
        const float thr = s * (MARGIN / CC);   // 0.5 * mean
        #pragma unroll
        for (int t = 0; t < 4; ++t) {
            c4[t].x += (ad[t].x < thr) ? 1.f : 0.f;
            c4[t].y += (ad[t].y < thr) ? 1.f : 0.f;
            c4[t].z += (ad[t].z < thr) ? 1.f : 0.f;
            c4[t].w += (ad[t].w < thr) ? 1.f : 0.f;
        }
    }
    float4* m4 = (float4*)mcsq;
    #pragma unroll
    for (int t = 0; t < 4; ++t) {
        float4 o;
        o.x = c4[t].x * c4[t].x;
        o.y = c4[t].y * c4[t].y;
        o.z = c4[t].z * c4[t].z;
        o.w = c4[t].w * c4[t].w;
        m4[(long)i * CC4 + lane + 64 * t] = o;
    }
}

// ---------------------------------------------------------------------------
// Kernel B: TRIANGULAR pair kernel — R4 frame (best measured: 89.0 µs,
// absmax 0.0) with the three 6-hop shuffle butterflies replaced by the
// HW-verified wred (2 LDS hops + 4 DPP). Everything else identical to R4:
// block = (ig, jt), ig <= jt (2080 uniform blocks); 4 waves, i = ig*4 + w;
// 4 j-rows (x + mcsq, 32 KB) LDS-staged once per block; one j at a time
// (low register pressure, ~90 VGPR live). Per-(i,j) arithmetic order and
// lane-0 reduction tree unchanged -> bit-exact (absmax must be 0).
// ---------------------------------------------------------------------------
__global__ __launch_bounds__(256) void pair_kernel(
    const float* __restrict__ x, const float* __restrict__ mcsq,
    const int* __restrict__ targets,
    float* __restrict__ pmax, float* __restrict__ pmin,
    float* __restrict__ pmaxT, float* __restrict__ pminT)
{
    const int tid  = threadIdx.x;
    const int lane = tid & 63;
    const int w    = tid >> 6;     // wave in block -> i within group
    const int b    = blockIdx.x;   // 0..2079

    // decode b -> (jt, ig): b = jt(jt+1)/2 + ig, ig in [0, jt]
    int jt = (int)((sqrtf(8.0f * (float)b + 1.0f) - 1.0f) * 0.5f);
    if (jt < 0) jt = 0;
    if (jt > 63) jt = 63;
    while (jt > 0 && (jt * (jt + 1)) / 2 > b) --jt;
    while (((jt + 1) * (jt + 2)) / 2 <= b) ++jt;
    const int ig = b - (jt * (jt + 1)) / 2;   // 0..jt
    const int i  = ig * 4 + w;                // wave's i-row
    const int j0 = jt * JPT;

    __shared__ float lds[8192];               // [0..4095]=x rows, [4096..]=mcsq rows
    float4* lds4 = (float4*)lds;

    const float4* x4 = (const float4*)x;
    const float4* m4 = (const float4*)mcsq;

    // --- hoist scalars ------------------------------------------------------
    const int ti = targets[i];
    int tj[4];
    #pragma unroll
    for (int q = 0; q < 4; ++q) tj[q] = targets[j0 + q];

    // --- i-row loads (per wave, registers) ---------------------------------
    float4 xi[4], mi[4];
    #pragma unroll
    for (int t = 0; t < 4; ++t) {
        const int c4 = lane + 64 * t;
        xi[t] = x4[(long)i * CC4 + c4];
        mi[t] = m4[(long)i * CC4 + c4];
    }

    // --- stage 4 j-rows of x and mcsq into LDS (256 thr x 8 float4) --------
    {
        float4 st[8];
        #pragma unroll
        for (int q = 0; q < 4; ++q) {
            st[q]     = x4[(long)(j0 + q) * CC4 + tid];
            st[4 + q] = m4[(long)(j0 + q) * CC4 + tid];
        }
        #pragma unroll
        for (int q = 0; q < 8; ++q) lds4[q * 256 + tid] = st[q];
    }
    __syncthreads();

    const float4* lx = lds4;                  // x rows: row*256 + c4
    const float4* lm = lds4 + 1024;           // mcsq rows

    float mx = 0.f, mn = INFINITY;

    #pragma unroll
    for (int jj = 0; jj < JPT; ++jj) {
        const int j = j0 + jj;

        // --- x row from LDS + L1 partial sum ----------------------------
        float4 xa[4];
        float s = 0.f;
        #pragma unroll
        for (int t = 0; t < 4; ++t) {
            xa[t] = lx[jj * 256 + lane + 64 * t];
            s += fabsf(xi[t].x - xa[t].x) + fabsf(xi[t].y - xa[t].y)
               + fabsf(xi[t].z - xa[t].z) + fabsf(xi[t].w - xa[t].w);
        }

        // --- issue mcsq LDS reads; latency covered by reduce ------------
        float4 ma[4];
        #pragma unroll
        for (int t = 0; t < 4; ++t) ma[t] = lm[jj * 256 + lane + 64 * t];

        const float thr = wred(s) * (MARGIN / CC);

        // --- masked pass ------------------------------------------------
        float ids = 0.f, md = 0.f;
        #pragma unroll
        for (int t = 0; t < 4; ++t) {
            #pragma unroll
            for (int u = 0; u < 4; ++u) {
                const float xiv = (&xi[t].x)[u];
                const float miv = (&mi[t].x)[u];
                const float xav = (&xa[t].x)[u];
                const float mav = (&ma[t].x)[u];
                const float d = xiv - xav;
                const float q = d * d;
                ids += (fabsf(d) < thr) ? q : 0.f;
                md  += q * miv * mav;
            }
        }
        const float rds = wred(ids);
        const float rmd = wred(md);

        // --- epilogue ---------------------------------------------------
        const float mod = sqrtf(fmaxf(rmd, 1e-12f));
        float idv = sqrtf(fmaxf(rds, 1e-12f));
        mx = fmaxf(mx, mod);
        if (tj[jj] != ti) mn = fminf(mn, idv); else idv = INFINITY;

        if (lane == 0) {                      // j-side (transposed) partial
            pmaxT[j * BB + i] = mod;
            pminT[j * BB + i] = idv;
        }
    }
    if (lane == 0) {                          // i-side partials
        pmax[i * NTILE + jt] = mx;
        pmin[i * NTILE + jt] = mn;
    }
}

// ---------------------------------------------------------------------------
// Kernel C: parallel final reduce (R4 form). One wave per row: i-side jt in
// [i>>2, 64) (1 guarded load), transposed i' < 4*(i>>2)+4 (4 guarded loads);
// 6-step max/min butterfly; atomicAdd of per_row/BB; last block publishes to
// d_out. Poisoned (never-written) slots are never read.
// ---------------------------------------------------------------------------
__global__ __launch_bounds__(64) void final_kernel(
    const float* __restrict__ pmax, const float* __restrict__ pmin,
    const float* __restrict__ pmaxT, const float* __restrict__ pminT,
    float* __restrict__ acc, unsigned int* __restrict__ cnt_g,
    float* __restrict__ out)
{
    const int i = blockIdx.x;       // row
    const int lane = threadIdx.x;
    const int s = i >> 2;
    float mx = 0.f, mn = INFINITY;
    const int t = s + lane;
    if (t < NTILE) {
        mx = fmaxf(mx, pmax[i * NTILE + t]);
        mn = fminf(mn, pmin[i * NTILE + t]);
    }
    const int pv = 4 * s + 4;       // transposed valid i' count
    #pragma unroll
    for (int q = 0; q < 4; ++q) {
        const int c = lane + 64 * q;
        if (c < pv) {
            mx = fmaxf(mx, pmaxT[i * BB + c]);
            mn = fminf(mn, pminT[i * BB + c]);
        }
    }
    #pragma unroll
    for (int off = 32; off > 0; off >>= 1) {
        mx = fmaxf(mx, __shfl_xor(mx, off, 64));
        mn = fminf(mn, __shfl_xor(mn, off, 64));
    }
    if (lane == 0) {
        const float per = fmaxf(mx * 10.f - mn, 0.f);
        atomicAdd(acc, per * (1.0f / BB));
        __threadfence();
        const unsigned int old = atomicAdd(cnt_g, 1u);
        if (old == BB - 1) {
            __threadfence();
            out[0] = atomicAdd(acc, 0.0f);   // device-coherent read-back
        }
    }
}

extern "C" void kernel_launch(void* const* d_in, const int* in_sizes, int n_in,
                              void* d_out, int out_size, void* d_ws, size_t ws_size,
                              hipStream_t stream)
{
    const float* x       = (const float*)d_in[0];
    const int*   targets = (const int*)d_in[1];
    const int*   subs    = (const int*)d_in[2];
    const int*   m_count = (const int*)d_in[3];
    float* out  = (float*)d_out;

    float* mcsq  = (float*)d_ws;                  // BB*CC floats = 1 MB
    float* pmax  = mcsq  + (long)BB * CC;         // BB*NTILE
    float* pmin  = pmax  + BB * NTILE;            // BB*NTILE
    float* pmaxT = pmin  + BB * NTILE;            // BB*BB
    float* pminT = pmaxT + BB * BB;               // BB*BB
    float* acc   = pminT + BB * BB;               // 1
    unsigned int* cnt_g = (unsigned int*)(acc + 1);

    mcsq_kernel <<<BB,   64, 0, stream>>>(x, targets, subs, m_count, mcsq, acc, cnt_g);
    pair_kernel <<<2080, 256, 0, stream>>>(x, mcsq, targets, pmax, pmin, pmaxT, pminT);
    final_kernel<<<BB,   64, 0, stream>>>(pmax, pmin, pmaxT, pminT, acc, cnt_g, out);
}